// Round 1
// baseline (126.091 us; speedup 1.0000x reference)
//
#include <hip/hip_runtime.h>

// Problem constants (fixed by setup_inputs): B=256, J=17, H*W=3072.
#define HW          3072
#define N_TOTAL     (256 * 17 * 3072)     // 13,369,344 elements
#define NJOINTS     (256 * 17)            // 4352 (b,j) slots, each with one weight
#define F4_PER_J    (HW / 4)              // 768 float4s per joint
#define BLOCK       256
#define JPB         2                     // joints per block
#define NBLOCKS1    (NJOINTS / JPB)       // 2176 blocks, exact cover (no tail)
#define ITERS_PER_J (F4_PER_J / BLOCK)    // 3 float4s per thread per joint

// Kernel 1: weighted-SSE partial reduction, structure-aware.
//  - Each block owns JPB whole joints -> tw[j] is a block-uniform scalar load,
//    hoisted off the critical path (no per-iteration gather, no int division).
//  - All trip counts are compile-time constants -> full unroll: 12 independent
//    global_load_dwordx4 in flight per wave (vs ~2 in the grid-stride version).
//  - 2176 blocks = 8.5 blocks/CU -> good balance + plenty of waves for latency.
__global__ __launch_bounds__(BLOCK) void partial_sse_kernel(
    const float* __restrict__ out,
    const float* __restrict__ tgt,
    const float* __restrict__ tw,
    float* __restrict__ partials)
{
    const float4* __restrict__ o4 = (const float4*)out;
    const float4* __restrict__ t4 = (const float4*)tgt;

    const int tid = threadIdx.x;
    const int j0  = blockIdx.x * JPB;

    float acc = 0.0f;

    #pragma unroll
    for (int jj = 0; jj < JPB; ++jj) {
        const int j = j0 + jj;                  // flat (b*17 + joint) index
        const float w  = tw[j];                 // block-uniform -> scalar load
        const float w2 = w * w;

        float s = 0.0f;
        #pragma unroll
        for (int k = 0; k < ITERS_PER_J; ++k) {
            const int i = j * F4_PER_J + k * BLOCK + tid;
            float4 o = o4[i];
            float4 t = t4[i];
            float d0 = o.x - t.x;
            float d1 = o.y - t.y;
            float d2 = o.z - t.z;
            float d3 = o.w - t.w;
            s += d0 * d0 + d1 * d1 + d2 * d2 + d3 * d3;
        }
        acc += w2 * s;
    }

    // wave64 shuffle reduction
    #pragma unroll
    for (int off = 32; off > 0; off >>= 1)
        acc += __shfl_down(acc, off, 64);

    __shared__ float lds[BLOCK / 64];
    int lane = threadIdx.x & 63;
    int wave = threadIdx.x >> 6;
    if (lane == 0) lds[wave] = acc;
    __syncthreads();

    if (threadIdx.x == 0) {
        float s = 0.0f;
        #pragma unroll
        for (int w_i = 0; w_i < BLOCK / 64; ++w_i) s += lds[w_i];
        partials[blockIdx.x] = s;
    }
}

// Kernel 2: reduce NBLOCKS1 partials, scale, write the scalar loss.
__global__ __launch_bounds__(BLOCK) void final_reduce_kernel(
    const float* __restrict__ partials,
    float* __restrict__ out)
{
    float acc = 0.0f;
    for (int i = threadIdx.x; i < NBLOCKS1; i += BLOCK)
        acc += partials[i];

    #pragma unroll
    for (int off = 32; off > 0; off >>= 1)
        acc += __shfl_down(acc, off, 64);

    __shared__ float lds[BLOCK / 64];
    int lane = threadIdx.x & 63;
    int wave = threadIdx.x >> 6;
    if (lane == 0) lds[wave] = acc;
    __syncthreads();

    if (threadIdx.x == 0) {
        float s = 0.0f;
        #pragma unroll
        for (int w_i = 0; w_i < BLOCK / 64; ++w_i) s += lds[w_i];
        out[0] = 0.5f * s / (float)N_TOTAL;
    }
}

extern "C" void kernel_launch(void* const* d_in, const int* in_sizes, int n_in,
                              void* d_out, int out_size, void* d_ws, size_t ws_size,
                              hipStream_t stream)
{
    const float* output = (const float*)d_in[0];   // [256,17,64,48] f32
    const float* target = (const float*)d_in[1];   // [256,17,64,48] f32
    const float* tw     = (const float*)d_in[2];   // [256,17,1]     f32

    float* partials = (float*)d_ws;                // NBLOCKS1 floats (8.5 KB)

    partial_sse_kernel<<<NBLOCKS1, BLOCK, 0, stream>>>(output, target, tw, partials);
    final_reduce_kernel<<<1, BLOCK, 0, stream>>>(partials, (float*)d_out);
}

// Round 4
// 125.402 us; speedup vs baseline: 1.0055x; 1.0055x over previous
//
#include <hip/hip_runtime.h>

// Problem constants (fixed by setup_inputs): B=256, J=17, H*W=3072.
#define HW          3072
#define N_TOTAL     (256 * 17 * 3072)     // 13,369,344 elements
#define NJOINTS     (256 * 17)            // 4352 (b,j) slots, each with one weight
#define F4_PER_J    (HW / 4)              // 768 float4s per joint
#define BLOCK       256
#define JPB         2                     // joints per block
#define NBLOCKS1    (NJOINTS / JPB)       // 2176 blocks, exact cover (no tail)
#define ITERS_PER_J (F4_PER_J / BLOCK)    // 3 float4s per thread per joint

// Kernel 1: weighted-SSE partial reduction with NON-TEMPORAL input reads.
// Rationale: the harness's 256 MiB poison fill leaves L3 entirely dirty just
// before this kernel; normal (allocating) reads evict ~107 MB of that dirty
// poison -> writeback traffic to HBM *inside our kernel's window*, halving
// effective read BW. NT loads bypass L2/L3 allocation: no evictions, pure
// 107 MB read stream. Inputs were never cache-resident anyway (poison owns
// all of L3), so NT forfeits nothing.
// NT is expressed via the SCALAR __builtin_nontemporal_load (rocPRIM-proven
// path); the 4 adjacent 16B-aligned loads merge to global_load_dwordx4 nt.
__global__ __launch_bounds__(BLOCK) void partial_sse_kernel(
    const float* __restrict__ out,
    const float* __restrict__ tgt,
    const float* __restrict__ tw,
    float* __restrict__ partials)
{
    const int tid = threadIdx.x;
    const int j0  = blockIdx.x * JPB;

    float acc = 0.0f;

    #pragma unroll
    for (int jj = 0; jj < JPB; ++jj) {
        const int j = j0 + jj;                  // flat (b*17 + joint) index
        const float w  = tw[j];                 // block-uniform, tiny -> normal load
        const float w2 = w * w;

        float s = 0.0f;
        #pragma unroll
        for (int k = 0; k < ITERS_PER_J; ++k) {
            // element index of this thread's float4 (16B-aligned)
            const int e = (j * F4_PER_J + k * BLOCK + tid) * 4;
            float o0 = __builtin_nontemporal_load(out + e + 0);
            float o1 = __builtin_nontemporal_load(out + e + 1);
            float o2 = __builtin_nontemporal_load(out + e + 2);
            float o3 = __builtin_nontemporal_load(out + e + 3);
            float t0 = __builtin_nontemporal_load(tgt + e + 0);
            float t1 = __builtin_nontemporal_load(tgt + e + 1);
            float t2 = __builtin_nontemporal_load(tgt + e + 2);
            float t3 = __builtin_nontemporal_load(tgt + e + 3);
            float d0 = o0 - t0;
            float d1 = o1 - t1;
            float d2 = o2 - t2;
            float d3 = o3 - t3;
            s += d0 * d0 + d1 * d1 + d2 * d2 + d3 * d3;
        }
        acc += w2 * s;
    }

    // wave64 shuffle reduction
    #pragma unroll
    for (int off = 32; off > 0; off >>= 1)
        acc += __shfl_down(acc, off, 64);

    __shared__ float lds[BLOCK / 64];
    int lane = threadIdx.x & 63;
    int wave = threadIdx.x >> 6;
    if (lane == 0) lds[wave] = acc;
    __syncthreads();

    if (threadIdx.x == 0) {
        float s = 0.0f;
        #pragma unroll
        for (int w_i = 0; w_i < BLOCK / 64; ++w_i) s += lds[w_i];
        partials[blockIdx.x] = s;
    }
}

// Kernel 2: reduce NBLOCKS1 partials, scale, write the scalar loss.
// Partials were just written by k1 (L2-resident) -> normal loads here.
__global__ __launch_bounds__(BLOCK) void final_reduce_kernel(
    const float* __restrict__ partials,
    float* __restrict__ out)
{
    float acc = 0.0f;
    for (int i = threadIdx.x; i < NBLOCKS1; i += BLOCK)
        acc += partials[i];

    #pragma unroll
    for (int off = 32; off > 0; off >>= 1)
        acc += __shfl_down(acc, off, 64);

    __shared__ float lds[BLOCK / 64];
    int lane = threadIdx.x & 63;
    int wave = threadIdx.x >> 6;
    if (lane == 0) lds[wave] = acc;
    __syncthreads();

    if (threadIdx.x == 0) {
        float s = 0.0f;
        #pragma unroll
        for (int w_i = 0; w_i < BLOCK / 64; ++w_i) s += lds[w_i];
        out[0] = 0.5f * s / (float)N_TOTAL;
    }
}

extern "C" void kernel_launch(void* const* d_in, const int* in_sizes, int n_in,
                              void* d_out, int out_size, void* d_ws, size_t ws_size,
                              hipStream_t stream)
{
    const float* output = (const float*)d_in[0];   // [256,17,64,48] f32
    const float* target = (const float*)d_in[1];   // [256,17,64,48] f32
    const float* tw     = (const float*)d_in[2];   // [256,17,1]     f32

    float* partials = (float*)d_ws;                // NBLOCKS1 floats (8.5 KB)

    partial_sse_kernel<<<NBLOCKS1, BLOCK, 0, stream>>>(output, target, tw, partials);
    final_reduce_kernel<<<1, BLOCK, 0, stream>>>(partials, (float*)d_out);
}